// Round 1
// 1035.664 us; speedup vs baseline: 1.0198x; 1.0198x over previous
//
#include <hip/hip_runtime.h>
#include <math.h>

// out = softmax(s @ X[:-1]^T) @ X[1:]
//   X: (8192,1024) fp32, s: (8191,1024) fp32, out: (8191,1024) fp32
// R3: 8 waves x 64 keys/wave, BK=512, in-register softmax, deferred l.

#define NQ 8191
#define NK 8191
#define DD 1024
#define BQ 32
#define BK 512
#define KPAD 8192
#define QS 1032        // Qs stride (halfs)
#define PS 520         // Pb stride (halfs)
#define ITERS 16       // 8191/512 rounded up
#define NW 8           // waves per block
#define NT 512

typedef _Float16 half8 __attribute__((ext_vector_type(8)));
typedef float float4v __attribute__((ext_vector_type(4)));

__global__ void prep_k(const float* __restrict__ X, _Float16* __restrict__ Kh) {
    int idx = blockIdx.x * 256 + threadIdx.x;
    int row = idx >> 10;
    float v = (row < NK) ? X[idx] : 0.f;
    Kh[idx] = (_Float16)v;
}

__global__ void prep_vt(const float* __restrict__ X, _Float16* __restrict__ Vt) {
    __shared__ float tile[64][65];
    int d0 = blockIdx.x * 64;
    int k0 = blockIdx.y * 64;
    int tx = threadIdx.x;
    int ty = threadIdx.y;
    for (int i = 0; i < 16; ++i) {
        int k = k0 + ty * 16 + i;
        float v = (k < NK) ? X[(size_t)(k + 1) * DD + d0 + tx] : 0.f;
        tile[tx][ty * 16 + i] = v;
    }
    __syncthreads();
    for (int i = 0; i < 16; ++i) {
        int dl = ty * 16 + i;
        Vt[(size_t)(d0 + dl) * KPAD + k0 + tx] = (_Float16)tile[dl][tx];
    }
}

__launch_bounds__(NT, 2)
__global__ void flash(const float* __restrict__ s,
                      const _Float16* __restrict__ Kh,
                      const _Float16* __restrict__ Vt,
                      float* __restrict__ out) {
    __shared__ _Float16 Qs[BQ][QS];      // 66 KB, staged once
    __shared__ _Float16 Pb[BQ][PS];      // 33 KB
    __shared__ float Rm[NW][BQ];         // per-wave row maxes
    __shared__ float Rl[NW][BQ];         // epilogue l reduction

    const int t  = threadIdx.x;
    const int w  = t >> 6;      // wave 0..7
    const int l  = t & 63;
    const int ln = l & 15;
    const int q4 = l >> 4;
    const int q0 = blockIdx.x * BQ;

    // stage Q tile fp32->fp16 (vectorized)
    for (int e = t; e < BQ * DD / 4; e += NT) {
        int r = e >> 8, d4 = (e & 255) << 2;
        float4v v = (q0 + r < NQ) ? *(const float4v*)&s[(size_t)(q0 + r) * DD + d4]
                                  : (float4v){0.f, 0.f, 0.f, 0.f};
        Qs[r][d4]     = (_Float16)v[0];
        Qs[r][d4 + 1] = (_Float16)v[1];
        Qs[r][d4 + 2] = (_Float16)v[2];
        Qs[r][d4 + 3] = (_Float16)v[3];
    }
    __syncthreads();

    // O accumulator: wave w owns D chunk [w*128, w*128+128): 2 qfrag x 8 dtile
    float4v o[2][8];
    #pragma unroll
    for (int qf = 0; qf < 2; ++qf)
        #pragma unroll
        for (int dt = 0; dt < 8; ++dt)
            o[qf][dt] = (float4v){0.f, 0.f, 0.f, 0.f};

    // per-lane online softmax state, rows qf*16 + q4*4 + r
    float m_run[8], l_run[8];
    #pragma unroll
    for (int i = 0; i < 8; ++i) { m_run[i] = -INFINITY; l_run[i] = 0.f; }

    const _Float16* kbase = Kh + (size_t)(w * 64 + ln) * DD + q4 * 8;
    const _Float16* vbase = Vt + (size_t)(w * 128 + ln) * KPAD + q4 * 8;

    for (int it = 0; it < ITERS; ++it) {
        const int kb = it * BK;

        // ---- phase 1: S[32 q][64 keys of this wave], full-D contraction ----
        float4v sa[2][4];
        #pragma unroll
        for (int qf = 0; qf < 2; ++qf)
            #pragma unroll
            for (int kf = 0; kf < 4; ++kf)
                sa[qf][kf] = (float4v){0.f, 0.f, 0.f, 0.f};

        const _Float16* kp = kbase + (size_t)kb * DD;
        #pragma unroll 4
        for (int kk = 0; kk < 32; ++kk) {
            half8 qa = *(const half8*)(&Qs[ln][kk * 32 + q4 * 8]);
            half8 qb = *(const half8*)(&Qs[16 + ln][kk * 32 + q4 * 8]);
            #pragma unroll
            for (int kf = 0; kf < 4; ++kf) {
                half8 kf8 = *(const half8*)(kp + (size_t)kf * (16 * DD) + kk * 32);
                sa[0][kf] = __builtin_amdgcn_mfma_f32_16x16x32_f16(qa, kf8, sa[0][kf], 0, 0, 0);
                sa[1][kf] = __builtin_amdgcn_mfma_f32_16x16x32_f16(qb, kf8, sa[1][kf], 0, 0, 0);
            }
        }

        // key validity (only the very last key 8191 is ever invalid)
        bool bad[4];
        #pragma unroll
        for (int kf = 0; kf < 4; ++kf)
            bad[kf] = (kb + w * 64 + kf * 16 + ln) >= NK;

        // ---- in-register wave-local row max over 64 keys ----
        float pm[8];
        #pragma unroll
        for (int qf = 0; qf < 2; ++qf)
            #pragma unroll
            for (int r = 0; r < 4; ++r) {
                float v = -INFINITY;
                #pragma unroll
                for (int kf = 0; kf < 4; ++kf) {
                    float sv = bad[kf] ? -INFINITY : sa[qf][kf][r];
                    v = fmaxf(v, sv);
                }
                pm[qf * 4 + r] = v;
            }
        #pragma unroll
        for (int i = 0; i < 8; ++i) {
            float v = pm[i];
            v = fmaxf(v, __shfl_xor(v, 1, 64));
            v = fmaxf(v, __shfl_xor(v, 2, 64));
            v = fmaxf(v, __shfl_xor(v, 4, 64));
            v = fmaxf(v, __shfl_xor(v, 8, 64));
            pm[i] = v;
        }
        if (ln == 0) {
            #pragma unroll
            for (int qf = 0; qf < 2; ++qf)
                #pragma unroll
                for (int r = 0; r < 4; ++r)
                    Rm[w][qf * 16 + q4 * 4 + r] = pm[qf * 4 + r];
        }
        __syncthreads();

        // ---- global row max, alpha ----
        float mn[8], al[8];
        #pragma unroll
        for (int qf = 0; qf < 2; ++qf)
            #pragma unroll
            for (int r = 0; r < 4; ++r) {
                int row = qf * 16 + q4 * 4 + r;
                float v = m_run[qf * 4 + r];
                #pragma unroll
                for (int wv = 0; wv < NW; ++wv) v = fmaxf(v, Rm[wv][row]);
                mn[qf * 4 + r] = v;
                al[qf * 4 + r] = __expf(m_run[qf * 4 + r] - v);
                m_run[qf * 4 + r] = v;
            }

        // prefetch V kk=0 frags over the exp/scatter phase
        const _Float16* vp = vbase + kb;
        half8 vpre[8];
        #pragma unroll
        for (int dt = 0; dt < 8; ++dt)
            vpre[dt] = *(const half8*)(vp + (size_t)dt * (16 * KPAD));

        // ---- exp in-register, per-lane l accumulate, write P fp16 ----
        #pragma unroll
        for (int i = 0; i < 8; ++i) l_run[i] *= al[i];
        #pragma unroll
        for (int qf = 0; qf < 2; ++qf)
            #pragma unroll
            for (int kf = 0; kf < 4; ++kf) {
                int col = w * 64 + kf * 16 + ln;
                #pragma unroll
                for (int r = 0; r < 4; ++r) {
                    float p = bad[kf] ? 0.f : __expf(sa[qf][kf][r] - mn[qf * 4 + r]);
                    l_run[qf * 4 + r] += p;
                    Pb[qf * 16 + q4 * 4 + r][col] = (_Float16)p;
                }
            }

        // rescale O
        #pragma unroll
        for (int qf = 0; qf < 2; ++qf)
            #pragma unroll
            for (int dt = 0; dt < 8; ++dt)
                #pragma unroll
                for (int r = 0; r < 4; ++r)
                    o[qf][dt][r] *= al[qf * 4 + r];
        __syncthreads();

        // ---- phase 3: O += P . V (wave's 128-wide D chunk, all 512 keys) ----
        {
            half8 pa  = *(const half8*)(&Pb[ln][q4 * 8]);
            half8 pb_ = *(const half8*)(&Pb[16 + ln][q4 * 8]);
            #pragma unroll
            for (int dt = 0; dt < 8; ++dt) {
                o[0][dt] = __builtin_amdgcn_mfma_f32_16x16x32_f16(pa,  vpre[dt], o[0][dt], 0, 0, 0);
                o[1][dt] = __builtin_amdgcn_mfma_f32_16x16x32_f16(pb_, vpre[dt], o[1][dt], 0, 0, 0);
            }
        }
        #pragma unroll 2
        for (int kk = 1; kk < 16; ++kk) {
            half8 pa  = *(const half8*)(&Pb[ln][kk * 32 + q4 * 8]);
            half8 pb_ = *(const half8*)(&Pb[16 + ln][kk * 32 + q4 * 8]);
            #pragma unroll
            for (int dt = 0; dt < 8; ++dt) {
                half8 vf = *(const half8*)(vp + (size_t)dt * (16 * KPAD) + kk * 32);
                o[0][dt] = __builtin_amdgcn_mfma_f32_16x16x32_f16(pa,  vf, o[0][dt], 0, 0, 0);
                o[1][dt] = __builtin_amdgcn_mfma_f32_16x16x32_f16(pb_, vf, o[1][dt], 0, 0, 0);
            }
        }
    }

    // ---- epilogue: reduce l across lanes and waves, scale, store ----
    float lt[8];
    #pragma unroll
    for (int i = 0; i < 8; ++i) {
        float v = l_run[i];
        v += __shfl_xor(v, 1, 64);
        v += __shfl_xor(v, 2, 64);
        v += __shfl_xor(v, 4, 64);
        v += __shfl_xor(v, 8, 64);
        lt[i] = v;
    }
    if (ln == 0) {
        #pragma unroll
        for (int qf = 0; qf < 2; ++qf)
            #pragma unroll
            for (int r = 0; r < 4; ++r)
                Rl[w][qf * 16 + q4 * 4 + r] = lt[qf * 4 + r];
    }
    __syncthreads();

    float inv[8];
    #pragma unroll
    for (int qf = 0; qf < 2; ++qf)
        #pragma unroll
        for (int r = 0; r < 4; ++r) {
            int row = qf * 16 + q4 * 4 + r;
            float sum = 0.f;
            #pragma unroll
            for (int wv = 0; wv < NW; ++wv) sum += Rl[wv][row];
            inv[qf * 4 + r] = 1.f / sum;
        }

    #pragma unroll
    for (int qf = 0; qf < 2; ++qf)
        #pragma unroll
        for (int dt = 0; dt < 8; ++dt)
            #pragma unroll
            for (int r = 0; r < 4; ++r) {
                int row = q0 + qf * 16 + q4 * 4 + r;
                int col = w * 128 + dt * 16 + ln;
                if (row < NQ)
                    out[(size_t)row * DD + col] = o[qf][dt][r] * inv[qf * 4 + r];
            }
}

extern "C" void kernel_launch(void* const* d_in, const int* in_sizes, int n_in,
                              void* d_out, int out_size, void* d_ws, size_t ws_size,
                              hipStream_t stream) {
    const float* X = (const float*)d_in[0];
    const float* s = (const float*)d_in[1];
    float* out = (float*)d_out;

    _Float16* Kh = (_Float16*)d_ws;                 // 16 MiB
    _Float16* Vt = Kh + (size_t)KPAD * DD;          // 16 MiB

    prep_k<<<(KPAD * DD) / 256, 256, 0, stream>>>(X, Kh);
    prep_vt<<<dim3(DD / 64, KPAD / 64), dim3(64, 4), 0, stream>>>(X, Vt);
    flash<<<(NQ + BQ - 1) / BQ, NT, 0, stream>>>(s, Kh, Vt, out);
}